// Round 6
// baseline (235.049 us; speedup 1.0000x reference)
//
#include <hip/hip_runtime.h>

// MixSelfAttention (B=2, L=1024, H=8, E=64), float32 in/out. 7 dispatches:
//   D1 prep : k0 transpose Q,K -> Qc/Kc[bh][eg][t][4e]  (blocks 0..255)
//             kw tile-transpose W -> Wt[2048][1024]      (blocks 256..767)
//             k3tf top-35 of tf row norms -> Stf         (blocks 768..783)
//   D2 k1   : circular correlation partials acp[be][tc][tau][4e]
//   D3 k3t  : fused k2 (sum tc, square, sum e) + single-wave top-35 -> St
//   D4 gs   : ka2 gather Wg[bh][m][72] (blocks 0..255)
//             k4 sparse scores + softmax -> P[bh][m][72] (blocks 256..767)
//   D5 kb   : WVp[mc] partial = sum_m Wg*v   (18x16x4)
//   D6 kc   : WV = sum_mc WVp
//   D7 k6   : out = P @ WV (+bias row), 4 l per block

#define NTOP 35
#define NJ 70
#define LLMIN (-0x7FFFFFFFFFFFFFFFLL - 1)

static __device__ __forceinline__ void fma4(float4& a, float4 q, float4 k) {
  a.x = fmaf(q.x,k.x,a.x); a.y = fmaf(q.y,k.y,a.y);
  a.z = fmaf(q.z,k.z,a.z); a.w = fmaf(q.w,k.w,a.w);
}

// single-wave top-35: caller ensures threadIdx.x < 64 calls this, vals[1024] ready
static __device__ __forceinline__ void wave_top35(const float* vals, int* out) {
  int lane = threadIdx.x;
  long long kreg[16];
  long long lmax = LLMIN;
  #pragma unroll
  for (int s = 0; s < 16; ++s) {
    int l = (s << 6) + lane;
    long long key = ((long long)(int)__float_as_uint(vals[l]) << 32)
                    | (unsigned int)(1023 - l);
    kreg[s] = key;
    lmax = key > lmax ? key : lmax;
  }
  for (int it = 0; it < NTOP; ++it) {
    long long g = lmax;
    #pragma unroll
    for (int off = 1; off < 64; off <<= 1) {
      long long o = __shfl_xor(g, off);
      g = o > g ? o : g;
    }
    if (lane == 0) out[it] = 1023 - (int)(g & 0xFFFFFFFFLL);
    if (lmax == g) {                    // unique owner (l encoded in key)
      lmax = LLMIN;
      #pragma unroll
      for (int s = 0; s < 16; ++s) {
        if (kreg[s] == g) kreg[s] = LLMIN;
        lmax = kreg[s] > lmax ? kreg[s] : lmax;
      }
    }
  }
}

// ---------------- D1 prep: k0 | kw | k3tf ----------------
__global__ __launch_bounds__(256) void prep(
    const float* __restrict__ q, const float* __restrict__ k,
    const float* __restrict__ tfq, const float* __restrict__ w,
    float* __restrict__ Qc, float* __restrict__ Kc,
    float* __restrict__ Wt, int* __restrict__ Stf) {
  __shared__ float4 smbuf[1040];        // 16640 B: kw tile / k3tf vals
  float* f = reinterpret_cast<float*>(smbuf);
  int bid = blockIdx.x;
  int tid = threadIdx.x;
  if (bid < 256) {                      // ---- k0 ----
    int bh = bid >> 4;  int t0 = (bid & 15) << 6;
    int b = bh >> 3, h = bh & 7;
    int ti = tid & 63;  int eg4 = tid >> 6;
    int t = t0 + ti;
    size_t base = (((size_t)(b*1024 + t)*8 + h) << 6) + (eg4 << 4);
    const float4* qp = reinterpret_cast<const float4*>(q + base);
    const float4* kp = reinterpret_cast<const float4*>(k + base);
    float4* Qc4 = reinterpret_cast<float4*>(Qc);
    float4* Kc4 = reinterpret_cast<float4*>(Kc);
    #pragma unroll
    for (int kk = 0; kk < 4; ++kk) {
      size_t idx = (size_t)(bh*16 + (eg4*4 + kk))*1024 + t;
      Qc4[idx] = qp[kk];
      Kc4[idx] = kp[kk];
    }
  } else if (bid < 768) {               // ---- kw ----
    int wid = bid - 256;
    int c0 = (wid & 31) << 6, r0 = (wid >> 5) << 6;
    float* tile = f;                    // 64*65 floats
    #pragma unroll
    for (int s = 0; s < 16; ++s) {
      int idx = tid + (s << 8);
      int r = idx >> 6, c = idx & 63;
      tile[r*65 + c] = w[(size_t)(r0 + r)*2048 + c0 + c];
    }
    __syncthreads();
    #pragma unroll
    for (int s = 0; s < 16; ++s) {
      int idx = tid + (s << 8);
      int c = idx >> 6, r = idx & 63;
      Wt[(size_t)(c0 + c)*1024 + r0 + r] = tile[r*65 + c];
    }
  } else {                              // ---- k3tf ----
    int bh = bid - 768;
    int b = bh >> 3, h = bh & 7;
    float* vals = f;                    // 1024 floats
    for (int l = tid; l < 1024; l += 256) {
      const float4* p = reinterpret_cast<const float4*>(
          tfq + (((size_t)(b*1024 + l)*8 + h) << 6));
      float s = 0.f;
      #pragma unroll
      for (int i = 0; i < 16; ++i) {
        float4 v = p[i];
        s += v.x*v.x + v.y*v.y + v.z*v.z + v.w*v.w;
      }
      vals[l] = s;
    }
    __syncthreads();
    if (tid < 64) wave_top35(vals, Stf + bh*40);
  }
}

// ---------------- D2 k1: correlation partials over 256-wide t-chunks ----------------
__global__ __launch_bounds__(256) void k1_corr(
    const float* __restrict__ Qc, const float* __restrict__ Kc,
    float* __restrict__ acp) {
  int gid = blockIdx.x;                 // 1024 = 16 bh | 16 eg | 4 tc
  int bh = gid & 15;  int eg = (gid >> 4) & 15;  int tc = gid >> 8;
  __shared__ float4 QP[1024];           // plane-major: [u=r&3][r>>2]
  __shared__ float4 Ks[256];
  int tid = threadIdx.x;
  const float4* Qg = reinterpret_cast<const float4*>(Qc) + (size_t)(bh*16+eg)*1024;
  const float4* Kg = reinterpret_cast<const float4*>(Kc) + (size_t)(bh*16+eg)*1024;
  int t0 = tc << 8;
  for (int r = tid; r < 1024; r += 256)
    QP[(r & 3)*256 + (r >> 2)] = Qg[r];
  Ks[tid] = Kg[t0 + tid];
  __syncthreads();
  float4 a0 = make_float4(0,0,0,0), a1 = a0, a2 = a0, a3 = a0;
  int i0 = ((t0 >> 2) + tid) & 255;
  float4 q0 = QP[i0], q1 = QP[256 + i0], q2 = QP[512 + i0], q3 = QP[768 + i0];
  int base = (t0 >> 2) + 1 + tid;
  for (int a = 0; a < 64; ++a) {
    int ia = (base + a) & 255;
    int s4 = a << 2;
    float4 kv = Ks[s4];
    fma4(a0,q0,kv); fma4(a1,q1,kv); fma4(a2,q2,kv); fma4(a3,q3,kv);
    q0=q1; q1=q2; q2=q3; q3 = QP[ia];
    kv = Ks[s4+1];
    fma4(a0,q0,kv); fma4(a1,q1,kv); fma4(a2,q2,kv); fma4(a3,q3,kv);
    q0=q1; q1=q2; q2=q3; q3 = QP[256 + ia];
    kv = Ks[s4+2];
    fma4(a0,q0,kv); fma4(a1,q1,kv); fma4(a2,q2,kv); fma4(a3,q3,kv);
    q0=q1; q1=q2; q2=q3; q3 = QP[512 + ia];
    kv = Ks[s4+3];
    fma4(a0,q0,kv); fma4(a1,q1,kv); fma4(a2,q2,kv); fma4(a3,q3,kv);
    q0=q1; q1=q2; q2=q3; q3 = QP[768 + ia];
  }
  float4* out = reinterpret_cast<float4*>(acp)
              + (((size_t)((bh*16+eg)*4 + tc)) << 10) + (tid << 2);
  out[0]=a0; out[1]=a1; out[2]=a2; out[3]=a3;
}

// ---------------- D3 k3t: fused combine + single-wave top-35 ----------------
__global__ __launch_bounds__(256) void k3_topk_t(
    const float* __restrict__ acp, int* __restrict__ St) {
  int bh = blockIdx.x;                  // 16 blocks
  __shared__ float vals[1024];
  int tid = threadIdx.x;
  float acc0 = 0.f, acc1 = 0.f, acc2 = 0.f, acc3 = 0.f;
  for (int eg = 0; eg < 16; ++eg) {
    const float4* E = reinterpret_cast<const float4*>(acp)
                    + (((size_t)(bh*16 + eg)) << 12);
    #pragma unroll
    for (int p = 0; p < 4; ++p) {
      int tau = tid + (p << 8);
      float4 s0 = E[tau], s1 = E[1024+tau], s2 = E[2048+tau], s3 = E[3072+tau];
      float x = s0.x+s1.x+s2.x+s3.x;
      float y = s0.y+s1.y+s2.y+s3.y;
      float z = s0.z+s1.z+s2.z+s3.z;
      float w = s0.w+s1.w+s2.w+s3.w;
      float r = x*x + y*y + z*z + w*w;
      if (p == 0) acc0 += r; else if (p == 1) acc1 += r;
      else if (p == 2) acc2 += r; else acc3 += r;
    }
  }
  vals[tid]       = acc0;
  vals[tid + 256] = acc1;
  vals[tid + 512] = acc2;
  vals[tid + 768] = acc3;
  __syncthreads();
  if (tid < 64) wave_top35(vals, St + bh*40);
}

// ---------------- D4 gs: ka2 | k4 ----------------
__global__ __launch_bounds__(256) void gs_gather_scores(
    const float* __restrict__ q, const float* __restrict__ k,
    const float* __restrict__ tfq,
    const float* __restrict__ Wt, const float* __restrict__ bias,
    const int* __restrict__ St, const int* __restrict__ Stf,
    float* __restrict__ Wg, float* __restrict__ P) {
  __shared__ float4 smbuf[1712];        // 27392 B
  float* f = reinterpret_cast<float*>(smbuf);
  int bid = blockIdx.x;
  int tid = threadIdx.x;
  if (bid < 256) {                      // ---- ka2 ----
    int bh = bid >> 4;  int m0 = (bid & 15) << 6;
    int* cols = reinterpret_cast<int*>(f);      // 72 ints
    float* Wlds = f + 72;                       // 72*65 floats
    if (tid < NTOP)      cols[tid] = St[bh*40 + tid];
    else if (tid < NJ)   cols[tid] = 1024 + Stf[bh*40 + tid - NTOP];
    else if (tid < 72)   cols[tid] = (tid == NJ) ? -1 : -2;
    __syncthreads();
    for (int i = tid; i < 72*64; i += 256) {
      int j = i >> 6, mm = i & 63;
      int c = cols[j];
      float v = (c >= 0) ? Wt[(size_t)c*1024 + m0 + mm]
                         : ((c == -1) ? bias[m0 + mm] : 0.f);
      Wlds[j*65 + mm] = v;
    }
    __syncthreads();
    float* dst = Wg + ((size_t)bh*1024 + m0)*72;
    for (int i = tid; i < 64*72; i += 256) {
      int m = i / 72, j = i - m*72;
      dst[i] = Wlds[j*65 + m];
    }
  } else {                              // ---- k4: 512 blocks, 32-m chunks ----
    int gid = bid - 256;
    int bh = gid >> 5;  int m0 = (gid & 31) << 5;
    int b = bh >> 3, h = bh & 7;
    float* qs   = f;                    // 35*64
    float* ts   = f + 2240;             // 35*64
    float* sc   = f + 4480;             // 32*73
    float* invs = f + 6816;             // 32
    for (int i = tid; i < NTOP*64; i += 256) {
      int j = i >> 6, e = i & 63;
      qs[i] = q  [(((size_t)(b*1024 + St [bh*40 + j])*8 + h) << 6) + e];
      ts[i] = tfq[(((size_t)(b*1024 + Stf[bh*40 + j])*8 + h) << 6) + e];
    }
    __syncthreads();
    int mi = tid & 31, g = tid >> 5;    // 8 groups
    int br = g >> 2, g4 = g & 3;        // branch, j-offset
    int m = m0 + mi;
    const float* src = br ? tfq : k;
    float4 kr[16];
    const float4* p = reinterpret_cast<const float4*>(
        src + (((size_t)(b*1024 + m)*8 + h) << 6));
    #pragma unroll
    for (int i = 0; i < 16; ++i) kr[i] = p[i];
    const float4* fs4 = reinterpret_cast<const float4*>(br ? ts : qs);
    int sb = br ? NTOP : 0;
    for (int j = g4; j < NTOP; j += 4) {
      float s = 0.f;
      #pragma unroll
      for (int e4 = 0; e4 < 16; ++e4) {
        float4 qv = fs4[j*16 + e4];
        s += qv.x*kr[e4].x + qv.y*kr[e4].y + qv.z*kr[e4].z + qv.w*kr[e4].w;
      }
      sc[mi*73 + sb + j] = s * 0.125f;
    }
    __syncthreads();
    if (tid < 32) {
      float mx = -1e30f;
      for (int j = 0; j < NJ; ++j) mx = fmaxf(mx, sc[tid*73 + j]);
      float sum = 0.f;
      for (int j = 0; j < NJ; ++j) {
        float e = __expf(sc[tid*73 + j] - mx);
        sc[tid*73 + j] = e; sum += e;
      }
      invs[tid] = 1.0f / sum;
    }
    __syncthreads();
    float* Pb = P + ((size_t)bh*1024 + m0)*72;
    for (int i = tid; i < 32*72; i += 256) {
      int mm = i / 72, j = i - mm*72;
      Pb[i] = (j < NJ) ? sc[mm*73 + j] * invs[mm] : 0.f;
    }
  }
}

// ---------------- D5 kb: partial WV over 256-m chunk ----------------
__global__ __launch_bounds__(256) void kb_wv(
    const float* __restrict__ Wg, const float* __restrict__ values,
    float* __restrict__ WVp) {
  int jq = blockIdx.x;                  // 0..17
  int bh = blockIdx.y;                  // 0..15
  int mc = blockIdx.z;                  // 0..3
  int b = bh >> 3, h = bh & 7;
  int j0 = jq << 2;
  int tid = threadIdx.x;
  int d = tid & 63, mp = tid >> 6;
  int m0 = (mc << 8) + mp;
  float a0=0.f, a1=0.f, a2=0.f, a3=0.f;
  const float* Wgb = Wg + (size_t)bh*1024*72;
  #pragma unroll 16
  for (int i = 0; i < 64; ++i) {
    int m = m0 + (i << 2);
    float vv = values[(((size_t)(b*1024 + m)*8 + h) << 6) + d];
    float4 wv = *reinterpret_cast<const float4*>(Wgb + (size_t)m*72 + j0);
    a0 = fmaf(wv.x, vv, a0); a1 = fmaf(wv.y, vv, a1);
    a2 = fmaf(wv.z, vv, a2); a3 = fmaf(wv.w, vv, a3);
  }
  __shared__ float4 red[256];
  red[tid] = make_float4(a0, a1, a2, a3);
  __syncthreads();
  int jj = tid >> 6, dd = tid & 63;
  float4 r0 = red[dd], r1 = red[64+dd], r2 = red[128+dd], r3 = red[192+dd];
  float s;
  if (jj == 0)      s = r0.x + r1.x + r2.x + r3.x;
  else if (jj == 1) s = r0.y + r1.y + r2.y + r3.y;
  else if (jj == 2) s = r0.z + r1.z + r2.z + r3.z;
  else              s = r0.w + r1.w + r2.w + r3.w;
  WVp[(size_t)mc*73728 + ((size_t)bh*72 + j0 + jj)*64 + dd] = s;
}

// ---------------- D6 kc: WV = sum_mc WVp ----------------
__global__ __launch_bounds__(256) void kc_comb(
    const float* __restrict__ WVp, float* __restrict__ WV) {
  int idx = blockIdx.x*256 + threadIdx.x;
  WV[idx] = WVp[idx] + WVp[73728 + idx] + WVp[147456 + idx] + WVp[221184 + idx];
}

// ---------------- D7 k6: out, 4 l per block ----------------
__global__ __launch_bounds__(512) void k6_out(
    const float* __restrict__ P, const float* __restrict__ WV,
    float* __restrict__ out) {
  int lc = blockIdx.x, b = blockIdx.y;
  int l0 = lc << 2;
  int tid = threadIdx.x;
  int h = tid >> 6, d = tid & 63;
  int bh = b*8 + h;
  const float* Wv = WV + (size_t)bh*72*64;
  const float* P0 = P + ((size_t)bh*1024 + l0)*72;
  float base = Wv[NJ*64 + d];
  float a0 = base, a1 = base, a2 = base, a3 = base;
  for (int j = 0; j < NJ; ++j) {
    float wv = Wv[j*64 + d];
    a0 = fmaf(P0[j],       wv, a0);
    a1 = fmaf(P0[72 + j],  wv, a1);
    a2 = fmaf(P0[144 + j], wv, a2);
    a3 = fmaf(P0[216 + j], wv, a3);
  }
  size_t ob = (((size_t)(b*1024 + l0)*8 + h) << 6) + d;
  out[ob]        = a0;
  out[ob + 512]  = a1;
  out[ob + 1024] = a2;
  out[ob + 1536] = a3;
}

extern "C" void kernel_launch(void* const* d_in, const int* in_sizes, int n_in,
                              void* d_out, int out_size, void* d_ws, size_t ws_size,
                              hipStream_t stream) {
  const float* tfq  = (const float*)d_in[0];
  const float* q    = (const float*)d_in[1];
  const float* k    = (const float*)d_in[2];
  const float* v    = (const float*)d_in[3];
  const float* tw   = (const float*)d_in[5];
  const float* tb   = (const float*)d_in[6];
  float* out = (float*)d_out;

  char* ws = (char*)d_ws;
  float* acp = (float*)(ws);                        // 16,777,216
  int*   St  = (int*)  (ws + 16777216);             // 4 KB
  int*   Stf = (int*)  (ws + 16781312);             // 4 KB
  float* Qc  = (float*)(ws + 16785408);             // 4,194,304
  float* Kc  = (float*)(ws + 20979712);             // 4,194,304
  float* Wt  = (float*)(ws + 25174016);             // 8,388,608
  float* Wg  = (float*)(ws + 33562624);             // 4,718,592
  float* P   = (float*)(ws + 38281216);             // 4,718,592
  float* WV  = (float*)(ws + 42999808);             // 294,912
  float* WVp = (float*)(ws + 43294720);             // 1,179,648

  prep            <<<784, 256, 0, stream>>>(q, k, tfq, tw, Qc, Kc, Wt, Stf);
  k1_corr         <<<1024, 256, 0, stream>>>(Qc, Kc, acp);
  k3_topk_t       <<<16, 256, 0, stream>>>(acp, St);
  gs_gather_scores<<<768, 256, 0, stream>>>(q, k, tfq, Wt, tb, St, Stf, Wg, P);
  kb_wv           <<<dim3(18, 16, 4), 256, 0, stream>>>(Wg, v, WVp);
  kc_comb         <<<288, 256, 0, stream>>>(WVp, WV);
  k6_out          <<<dim3(256, 2), 512, 0, stream>>>(P, WV, out);
}

// Round 8
// 200.264 us; speedup vs baseline: 1.1737x; 1.1737x over previous
//
#include <hip/hip_runtime.h>

// MixSelfAttention (B=2, L=1024, H=8, E=64), float32 in/out. 5 dispatches:
//   D1 d1_prep: k1 circular-corr partials acp[be][tc][tau][4e] from RAW q,k
//               (blocks 0..1023) | kw tile-transpose W -> Wt[2048][1024]
//               (blocks 1024..1535)
//   D2 d2_topk: 32 blocks x 1024 thr; t: tc-combine+square+e-sum + top35 -> St
//               tf: row norms + top35 -> Stf   (single-wave selection)
//   D3 d3_gs  : gather Wg[bh][m][72] (0..255) | k4 scores+softmax -> P (256..767)
//   D4 kb_wv  : WVp[mc][bh][j][d] partial = sum_m Wg*v   (18x16x4)
//   D5 k6_out : Wv = sum_mc WVp (LDS-staged), out = P @ Wv + bias-row

#define NTOP 35
#define NJ 70
#define LLMIN (-0x7FFFFFFFFFFFFFFFLL - 1)

static __device__ __forceinline__ void fma4(float4& a, float4 q, float4 k) {
  a.x = fmaf(q.x,k.x,a.x); a.y = fmaf(q.y,k.y,a.y);
  a.z = fmaf(q.z,k.z,a.z); a.w = fmaf(q.w,k.w,a.w);
}

// single-wave top-35 (threadIdx.x<64 calls), vals[1024] ready, jax tie-break
static __device__ __forceinline__ void wave_top35(const float* vals, int* out) {
  int lane = threadIdx.x;
  long long kreg[16];
  long long lmax = LLMIN;
  #pragma unroll
  for (int s = 0; s < 16; ++s) {
    int l = (s << 6) + lane;
    long long key = ((long long)(int)__float_as_uint(vals[l]) << 32)
                    | (unsigned int)(1023 - l);
    kreg[s] = key;
    lmax = key > lmax ? key : lmax;
  }
  for (int it = 0; it < NTOP; ++it) {
    long long g = lmax;
    #pragma unroll
    for (int off = 1; off < 64; off <<= 1) {
      long long o = __shfl_xor(g, off);
      g = o > g ? o : g;
    }
    if (lane == 0) out[it] = 1023 - (int)(g & 0xFFFFFFFFLL);
    if (lmax == g) {                    // unique owner (l encoded in key)
      lmax = LLMIN;
      #pragma unroll
      for (int s = 0; s < 16; ++s) {
        if (kreg[s] == g) kreg[s] = LLMIN;
        lmax = kreg[s] > lmax ? kreg[s] : lmax;
      }
    }
  }
}

// ---------------- D1: k1 (raw q,k) | kw ----------------
__global__ __launch_bounds__(256) void d1_prep(
    const float* __restrict__ q, const float* __restrict__ k,
    const float* __restrict__ w,
    float* __restrict__ Wt, float* __restrict__ acp) {
  __shared__ float4 smbuf[1280];        // 20480 B
  int bid = blockIdx.x;
  int tid = threadIdx.x;
  if (bid < 1024) {                     // ---- k1 ----
    int bh = bid & 15;  int eg = (bid >> 4) & 15;  int tc = bid >> 8;
    int b = bh >> 3, h = bh & 7;
    float4* QP = smbuf;                 // plane-major [r&3][r>>2], 1024
    float4* Ks = smbuf + 1024;          // 256
    const float* qb  = q + (size_t)b*524288 + h*64 + eg*4;
    const float* kbp = k + (size_t)b*524288 + h*64 + eg*4;
    int t0 = tc << 8;
    for (int r = tid; r < 1024; r += 256)
      QP[(r & 3)*256 + (r >> 2)] =
          *reinterpret_cast<const float4*>(qb + (size_t)r*512);
    Ks[tid] = *reinterpret_cast<const float4*>(kbp + (size_t)(t0 + tid)*512);
    __syncthreads();
    float4 a0 = make_float4(0,0,0,0), a1 = a0, a2 = a0, a3 = a0;
    int i0 = ((t0 >> 2) + tid) & 255;
    float4 q0 = QP[i0], q1 = QP[256+i0], q2 = QP[512+i0], q3 = QP[768+i0];
    int base = (t0 >> 2) + 1 + tid;
    for (int a = 0; a < 64; ++a) {
      int ia = (base + a) & 255;
      int s4 = a << 2;
      float4 kv = Ks[s4];
      fma4(a0,q0,kv); fma4(a1,q1,kv); fma4(a2,q2,kv); fma4(a3,q3,kv);
      q0=q1; q1=q2; q2=q3; q3 = QP[ia];
      kv = Ks[s4+1];
      fma4(a0,q0,kv); fma4(a1,q1,kv); fma4(a2,q2,kv); fma4(a3,q3,kv);
      q0=q1; q1=q2; q2=q3; q3 = QP[256 + ia];
      kv = Ks[s4+2];
      fma4(a0,q0,kv); fma4(a1,q1,kv); fma4(a2,q2,kv); fma4(a3,q3,kv);
      q0=q1; q1=q2; q2=q3; q3 = QP[512 + ia];
      kv = Ks[s4+3];
      fma4(a0,q0,kv); fma4(a1,q1,kv); fma4(a2,q2,kv); fma4(a3,q3,kv);
      q0=q1; q1=q2; q2=q3; q3 = QP[768 + ia];
    }
    float4* o = reinterpret_cast<float4*>(acp)
              + (((size_t)((bh*16+eg)*4 + tc)) << 10) + (tid << 2);
    o[0]=a0; o[1]=a1; o[2]=a2; o[3]=a3;
  } else {                              // ---- kw ----
    int wid = bid - 1024;
    int c0 = (wid & 31) << 6, r0 = (wid >> 5) << 6;
    float* tile = reinterpret_cast<float*>(smbuf);   // 64*65 floats
    #pragma unroll
    for (int s = 0; s < 16; ++s) {
      int idx = tid + (s << 8);
      int r = idx >> 6, c = idx & 63;
      tile[r*65 + c] = w[(size_t)(r0 + r)*2048 + c0 + c];
    }
    __syncthreads();
    #pragma unroll
    for (int s = 0; s < 16; ++s) {
      int idx = tid + (s << 8);
      int c = idx >> 6, r = idx & 63;
      Wt[(size_t)(c0 + c)*1024 + r0 + r] = tile[r*65 + c];
    }
  }
}

// ---------------- D2: top-35 both branches, 1024 threads ----------------
__global__ __launch_bounds__(1024) void d2_topk(
    const float* __restrict__ acp, const float* __restrict__ tfq,
    int* __restrict__ St, int* __restrict__ Stf) {
  __shared__ float vals[1024];
  int bid = blockIdx.x;
  int tid = threadIdx.x;
  bool isT = bid < 16;
  int bh = isT ? bid : bid - 16;
  if (isT) {                            // t: combine tc chunks, square, sum e
    int tau = tid;
    const float4* A = reinterpret_cast<const float4*>(acp);
    float s = 0.f;
    #pragma unroll
    for (int eg = 0; eg < 16; ++eg) {
      const float4* E = A + (((size_t)(bh*16 + eg)) << 12);
      float4 c0 = E[tau], c1 = E[1024+tau], c2 = E[2048+tau], c3 = E[3072+tau];
      float x = c0.x+c1.x+c2.x+c3.x;
      float y = c0.y+c1.y+c2.y+c3.y;
      float z = c0.z+c1.z+c2.z+c3.z;
      float w = c0.w+c1.w+c2.w+c3.w;
      s += x*x + y*y + z*z + w*w;
    }
    vals[tau] = s;
  } else {                              // tf: row norms
    int b = bh >> 3, h = bh & 7;
    const float4* p = reinterpret_cast<const float4*>(
        tfq + (((size_t)(b*1024 + tid)*8 + h) << 6));
    float s = 0.f;
    #pragma unroll
    for (int i = 0; i < 16; ++i) {
      float4 vv = p[i];
      s += vv.x*vv.x + vv.y*vv.y + vv.z*vv.z + vv.w*vv.w;
    }
    vals[tid] = s;
  }
  __syncthreads();
  if (tid < 64) wave_top35(vals, (isT ? St : Stf) + bh*40);
}

// ---------------- D3: gather | k4 ----------------
__global__ __launch_bounds__(256) void d3_gs(
    const float* __restrict__ q, const float* __restrict__ k,
    const float* __restrict__ tfq,
    const float* __restrict__ Wt, const float* __restrict__ bias,
    const int* __restrict__ St, const int* __restrict__ Stf,
    float* __restrict__ Wg, float* __restrict__ P) {
  __shared__ float4 smbuf[1712];        // 27392 B
  float* f = reinterpret_cast<float*>(smbuf);
  int bid = blockIdx.x;
  int tid = threadIdx.x;
  if (bid < 256) {                      // ---- gather ----
    int bh = bid >> 4;  int m0 = (bid & 15) << 6;
    int* cols = reinterpret_cast<int*>(f);      // 72
    float* Wlds = f + 72;                       // 72*65
    if (tid < NTOP)      cols[tid] = St[bh*40 + tid];
    else if (tid < NJ)   cols[tid] = 1024 + Stf[bh*40 + tid - NTOP];
    else if (tid < 72)   cols[tid] = (tid == NJ) ? -1 : -2;
    __syncthreads();
    for (int i = tid; i < 72*64; i += 256) {
      int j = i >> 6, mm = i & 63;
      int c = cols[j];
      float vv = (c >= 0) ? Wt[(size_t)c*1024 + m0 + mm]
                          : ((c == -1) ? bias[m0 + mm] : 0.f);
      Wlds[j*65 + mm] = vv;
    }
    __syncthreads();
    float* dst = Wg + ((size_t)bh*1024 + m0)*72;
    for (int i = tid; i < 64*72; i += 256) {
      int m = i / 72, j = i - m*72;
      dst[i] = Wlds[j*65 + m];
    }
  } else {                              // ---- k4 ----
    int gid = bid - 256;
    int bh = gid >> 5;  int m0 = (gid & 31) << 5;
    int b = bh >> 3, h = bh & 7;
    float* qs   = f;                    // 35*64
    float* ts   = f + 2240;
    float* sc   = f + 4480;             // 32*73
    float* invs = f + 6816;             // 32
    for (int i = tid; i < NTOP*64; i += 256) {
      int j = i >> 6, e = i & 63;
      qs[i] = q  [(((size_t)(b*1024 + St [bh*40 + j])*8 + h) << 6) + e];
      ts[i] = tfq[(((size_t)(b*1024 + Stf[bh*40 + j])*8 + h) << 6) + e];
    }
    __syncthreads();
    int mi = tid & 31, g = tid >> 5;
    int br = g >> 2, g4 = g & 3;
    int m = m0 + mi;
    const float* src = br ? tfq : k;
    float4 kr[16];
    const float4* p = reinterpret_cast<const float4*>(
        src + (((size_t)(b*1024 + m)*8 + h) << 6));
    #pragma unroll
    for (int i = 0; i < 16; ++i) kr[i] = p[i];
    const float4* fs4 = reinterpret_cast<const float4*>(br ? ts : qs);
    int sb = br ? NTOP : 0;
    for (int j = g4; j < NTOP; j += 4) {
      float s = 0.f;
      #pragma unroll
      for (int e4 = 0; e4 < 16; ++e4) {
        float4 qv = fs4[j*16 + e4];
        s += qv.x*kr[e4].x + qv.y*kr[e4].y + qv.z*kr[e4].z + qv.w*kr[e4].w;
      }
      sc[mi*73 + sb + j] = s * 0.125f;
    }
    __syncthreads();
    if (tid < 32) {
      float mx = -1e30f;
      for (int j = 0; j < NJ; ++j) mx = fmaxf(mx, sc[tid*73 + j]);
      float sum = 0.f;
      for (int j = 0; j < NJ; ++j) {
        float e = __expf(sc[tid*73 + j] - mx);
        sc[tid*73 + j] = e; sum += e;
      }
      invs[tid] = 1.0f / sum;
    }
    __syncthreads();
    float* Pb = P + ((size_t)bh*1024 + m0)*72;
    for (int i = tid; i < 32*72; i += 256) {
      int mm = i / 72, j = i - mm*72;
      Pb[i] = (j < NJ) ? sc[mm*73 + j] * invs[mm] : 0.f;
    }
  }
}

// ---------------- D4: partial WV over 256-m chunk ----------------
__global__ __launch_bounds__(256) void kb_wv(
    const float* __restrict__ Wg, const float* __restrict__ values,
    float* __restrict__ WVp) {
  int jq = blockIdx.x;                  // 0..17
  int bh = blockIdx.y;                  // 0..15
  int mc = blockIdx.z;                  // 0..3
  int b = bh >> 3, h = bh & 7;
  int j0 = jq << 2;
  int tid = threadIdx.x;
  int d = tid & 63, mp = tid >> 6;
  int m0 = (mc << 8) + mp;
  float a0=0.f, a1=0.f, a2=0.f, a3=0.f;
  const float* Wgb = Wg + (size_t)bh*1024*72;
  #pragma unroll 16
  for (int i = 0; i < 64; ++i) {
    int m = m0 + (i << 2);
    float vv = values[(((size_t)(b*1024 + m)*8 + h) << 6) + d];
    float4 wv = *reinterpret_cast<const float4*>(Wgb + (size_t)m*72 + j0);
    a0 = fmaf(wv.x, vv, a0); a1 = fmaf(wv.y, vv, a1);
    a2 = fmaf(wv.z, vv, a2); a3 = fmaf(wv.w, vv, a3);
  }
  __shared__ float4 red[256];
  red[tid] = make_float4(a0, a1, a2, a3);
  __syncthreads();
  int jj = tid >> 6, dd = tid & 63;
  float4 r0 = red[dd], r1 = red[64+dd], r2 = red[128+dd], r3 = red[192+dd];
  float s;
  if (jj == 0)      s = r0.x + r1.x + r2.x + r3.x;
  else if (jj == 1) s = r0.y + r1.y + r2.y + r3.y;
  else if (jj == 2) s = r0.z + r1.z + r2.z + r3.z;
  else              s = r0.w + r1.w + r2.w + r3.w;
  WVp[(size_t)mc*73728 + ((size_t)bh*72 + j0 + jj)*64 + dd] = s;
}

// ---------------- D5: out = P @ (sum_mc WVp), 4 l per block ----------------
__global__ __launch_bounds__(512) void k6_out(
    const float* __restrict__ P, const float* __restrict__ WVp,
    float* __restrict__ out) {
  __shared__ float wvs[71*64];          // 18176 B: combined Wv for this bh-set? no: per (b,h) pair below
  int lc = blockIdx.x, b = blockIdx.y;
  int l0 = lc << 2;
  int tid = threadIdx.x;
  int h = tid >> 6, d = tid & 63;
  int bh = b*8 + h;
  // stage Wv = sum_mc WVp for each h... Wv differs per h; wvs holds only rows
  // for this thread's bh -> must stage per-h: 8 h x 71 x 64 too big. Instead
  // each thread sums chunks inline (4 loads per j) -- L2-resident.
  (void)wvs;
  const float* W0 = WVp + (size_t)bh*4608;
  const float* W1 = W0 + 73728;
  const float* W2 = W1 + 73728;
  const float* W3 = W2 + 73728;
  const float* P0 = P + ((size_t)bh*1024 + l0)*72;
  int x = NJ*64 + d;
  float base = W0[x] + W1[x] + W2[x] + W3[x];
  float a0 = base, a1 = base, a2 = base, a3 = base;
  for (int j = 0; j < NJ; ++j) {
    int y = j*64 + d;
    float wv = W0[y] + W1[y] + W2[y] + W3[y];
    a0 = fmaf(P0[j],       wv, a0);
    a1 = fmaf(P0[72 + j],  wv, a1);
    a2 = fmaf(P0[144 + j], wv, a2);
    a3 = fmaf(P0[216 + j], wv, a3);
  }
  size_t ob = (((size_t)(b*1024 + l0)*8 + h) << 6) + d;
  out[ob]        = a0;
  out[ob + 512]  = a1;
  out[ob + 1024] = a2;
  out[ob + 1536] = a3;
}

extern "C" void kernel_launch(void* const* d_in, const int* in_sizes, int n_in,
                              void* d_out, int out_size, void* d_ws, size_t ws_size,
                              hipStream_t stream) {
  const float* tfq  = (const float*)d_in[0];
  const float* q    = (const float*)d_in[1];
  const float* k    = (const float*)d_in[2];
  const float* v    = (const float*)d_in[3];
  const float* tw   = (const float*)d_in[5];
  const float* tb   = (const float*)d_in[6];
  float* out = (float*)d_out;

  char* ws = (char*)d_ws;
  float* acp = (float*)(ws);                        // 16,777,216
  int*   St  = (int*)  (ws + 16777216);             // 4 KB
  int*   Stf = (int*)  (ws + 16781312);             // 4 KB
  float* Wt  = (float*)(ws + 16785408);             // 8,388,608
  float* Wg  = (float*)(ws + 25174016);             // 4,718,592
  float* P   = (float*)(ws + 29892608);             // 4,718,592
  float* WVp = (float*)(ws + 34611200);             // 1,179,648

  d1_prep<<<1536, 256, 0, stream>>>(q, k, tw, Wt, acp);
  d2_topk<<<32, 1024, 0, stream>>>(acp, tfq, St, Stf);
  d3_gs  <<<768, 256, 0, stream>>>(q, k, tfq, Wt, tb, St, Stf, Wg, P);
  kb_wv  <<<dim3(18, 16, 4), 256, 0, stream>>>(Wg, v, WVp);
  k6_out <<<dim3(256, 2), 512, 0, stream>>>(P, WVp, out);
}

// Round 9
// 178.288 us; speedup vs baseline: 1.3184x; 1.1233x over previous
//
#include <hip/hip_runtime.h>

// MixSelfAttention (B=2, L=1024, H=8, E=64), float32 in/out. 4 dispatches:
//   D1 d1: k1 circular-corr partials from RAW q,k, 8 taus/thread rolling window
//          (blocks 0..511: bh x eg x tcpair) | kw tile-transpose W -> Wt (512..1023)
//   D2 d2: 32 blocks x 1024 thr; t: tc-combine+square+e-sum + top35 -> St
//          tf: row norms + top35 -> Stf (single-wave selection)
//   D3 d3: kb direct-Wt WVp partials (blocks 0..1151) | k4 scores+softmax -> P
//          (blocks 1152..1663)  [no gather, no Wg]
//   D4 k6: per-bh blocks; Wv=sum_mc WVp staged in LDS + transposed P chunk;
//          out = P @ Wv + bias-row

#define NTOP 35
#define NJ 70
#define LLMIN (-0x7FFFFFFFFFFFFFFFLL - 1)

static __device__ __forceinline__ void fma4(float4& a, float4 q, float4 k) {
  a.x = fmaf(q.x,k.x,a.x); a.y = fmaf(q.y,k.y,a.y);
  a.z = fmaf(q.z,k.z,a.z); a.w = fmaf(q.w,k.w,a.w);
}

// single-wave top-35 (threadIdx.x<64 calls), vals[1024] ready, jax tie-break
static __device__ __forceinline__ void wave_top35(const float* vals, int* out) {
  int lane = threadIdx.x;
  long long kreg[16];
  long long lmax = LLMIN;
  #pragma unroll
  for (int s = 0; s < 16; ++s) {
    int l = (s << 6) + lane;
    long long key = ((long long)(int)__float_as_uint(vals[l]) << 32)
                    | (unsigned int)(1023 - l);
    kreg[s] = key;
    lmax = key > lmax ? key : lmax;
  }
  for (int it = 0; it < NTOP; ++it) {
    long long g = lmax;
    #pragma unroll
    for (int off = 1; off < 64; off <<= 1) {
      long long o = __shfl_xor(g, off);
      g = o > g ? o : g;
    }
    if (lane == 0) out[it] = 1023 - (int)(g & 0xFFFFFFFFLL);
    if (lmax == g) {
      lmax = LLMIN;
      #pragma unroll
      for (int s = 0; s < 16; ++s) {
        if (kreg[s] == g) kreg[s] = LLMIN;
        lmax = kreg[s] > lmax ? kreg[s] : lmax;
      }
    }
  }
}

// ---------------- D1: k1 (8 tau/thread) | kw ----------------
__global__ __launch_bounds__(256, 4) void d1_prep(
    const float* __restrict__ q, const float* __restrict__ k,
    const float* __restrict__ w,
    float* __restrict__ Wt, float* __restrict__ acp) {
  __shared__ float4 smbuf[1536];        // 24576 B: QP[1024] + Ks[512] / kw tile
  int bid = blockIdx.x;
  int tid = threadIdx.x;
  if (bid < 512) {                      // ---- k1 ----
    int bh = bid & 15;  int eg = (bid >> 4) & 15;  int tcp = bid >> 8; // 0/1
    int b = bh >> 3, h = bh & 7;
    float4* QP = smbuf;                 // 8-plane: phys = (r&7)*128 + (r>>3)
    float4* Ks = smbuf + 1024;          // 512 rows (this tc-pair's 512 t's)
    const float* qb  = q + (size_t)b*524288 + h*64 + eg*4;
    const float* kbp = k + (size_t)b*524288 + h*64 + eg*4;
    int tbase0 = tcp << 9;              // 512*tcp
    for (int r = tid; r < 1024; r += 256)
      QP[(r & 7)*128 + (r >> 3)] =
          *reinterpret_cast<const float4*>(qb + (size_t)r*512);
    for (int i = tid; i < 512; i += 256)
      Ks[i] = *reinterpret_cast<const float4*>(kbp + (size_t)(tbase0 + i)*512);
    __syncthreads();
    int tg = tid & 127, ts = tid >> 7;  // 8 taus each; ts picks 256-t subchunk
    int tb = tg << 3;
    int tstart = tbase0 + (ts << 8);
    float4 acc[8];
    float4 wnd[8];
    #pragma unroll
    for (int i = 0; i < 8; ++i) {
      acc[i] = make_float4(0,0,0,0);
      int r = (tstart + tb + i) & 1023;
      wnd[i] = QP[(r & 7)*128 + (r >> 3)];
    }
    int ksb = ts << 8;
    for (int t8 = 0; t8 < 256; t8 += 8) {
      #pragma unroll
      for (int s = 0; s < 8; ++s) {
        float4 kv = Ks[ksb + t8 + s];
        #pragma unroll
        for (int i = 0; i < 8; ++i)
          fma4(acc[i], wnd[(s + i) & 7], kv);
        int rn = (tstart + t8 + s + tb + 8) & 1023;
        wnd[s & 7] = QP[(rn & 7)*128 + (rn >> 3)];
      }
    }
    float4* o = reinterpret_cast<float4*>(acp)
              + (((size_t)((bh*16+eg)*4 + (tcp*2 + ts))) << 10) + tb;
    #pragma unroll
    for (int i = 0; i < 8; ++i) o[i] = acc[i];
  } else {                              // ---- kw ----
    int wid = bid - 512;
    int c0 = (wid & 31) << 6, r0 = (wid >> 5) << 6;
    float* tile = reinterpret_cast<float*>(smbuf);   // 64*65 floats
    #pragma unroll
    for (int s = 0; s < 16; ++s) {
      int idx = tid + (s << 8);
      int r = idx >> 6, c = idx & 63;
      tile[r*65 + c] = w[(size_t)(r0 + r)*2048 + c0 + c];
    }
    __syncthreads();
    #pragma unroll
    for (int s = 0; s < 16; ++s) {
      int idx = tid + (s << 8);
      int c = idx >> 6, r = idx & 63;
      Wt[(size_t)(c0 + c)*1024 + r0 + r] = tile[r*65 + c];
    }
  }
}

// ---------------- D2: top-35 both branches, 1024 threads ----------------
__global__ __launch_bounds__(1024) void d2_topk(
    const float* __restrict__ acp, const float* __restrict__ tfq,
    int* __restrict__ St, int* __restrict__ Stf) {
  __shared__ float vals[1024];
  int bid = blockIdx.x;
  int tid = threadIdx.x;
  bool isT = bid < 16;
  int bh = isT ? bid : bid - 16;
  if (isT) {
    int tau = tid;
    const float4* A = reinterpret_cast<const float4*>(acp);
    float s = 0.f;
    #pragma unroll
    for (int eg = 0; eg < 16; ++eg) {
      const float4* E = A + (((size_t)(bh*16 + eg)) << 12);
      float4 c0 = E[tau], c1 = E[1024+tau], c2 = E[2048+tau], c3 = E[3072+tau];
      float x = c0.x+c1.x+c2.x+c3.x;
      float y = c0.y+c1.y+c2.y+c3.y;
      float z = c0.z+c1.z+c2.z+c3.z;
      float w = c0.w+c1.w+c2.w+c3.w;
      s += x*x + y*y + z*z + w*w;
    }
    vals[tau] = s;
  } else {
    int b = bh >> 3, h = bh & 7;
    const float4* p = reinterpret_cast<const float4*>(
        tfq + (((size_t)(b*1024 + tid)*8 + h) << 6));
    float s = 0.f;
    #pragma unroll
    for (int i = 0; i < 16; ++i) {
      float4 vv = p[i];
      s += vv.x*vv.x + vv.y*vv.y + vv.z*vv.z + vv.w*vv.w;
    }
    vals[tid] = s;
  }
  __syncthreads();
  if (tid < 64) wave_top35(vals, (isT ? St : Stf) + bh*40);
}

// ---------------- D3: kb (direct Wt) | k4 ----------------
__global__ __launch_bounds__(256) void d3_mix(
    const float* __restrict__ q, const float* __restrict__ k,
    const float* __restrict__ tfq,
    const float* __restrict__ Wt, const float* __restrict__ bias,
    const float* __restrict__ values,
    const int* __restrict__ St, const int* __restrict__ Stf,
    float* __restrict__ WVp, float* __restrict__ P) {
  __shared__ float4 smbuf[1712];        // 27392 B (k4); kb uses first 4 KB
  float* f = reinterpret_cast<float*>(smbuf);
  int bid = blockIdx.x;
  int tid = threadIdx.x;
  if (bid < 1152) {                     // ---- kb: WVp partial, direct Wt ----
    int jq = bid / 64;                  // 0..17
    int rem = bid - jq*64;
    int bh = rem >> 2, mc = rem & 3;
    int b = bh >> 3, h = bh & 7;
    int j0 = jq << 2;
    // per-j column -> base pointer + scale (block-uniform)
    const float* pj[4]; float zj[4];
    #pragma unroll
    for (int x = 0; x < 4; ++x) {
      int j = j0 + x;
      if (j < NTOP)      { pj[x] = Wt + (size_t)St [bh*40 + j]*1024;        zj[x] = 1.f; }
      else if (j < NJ)   { pj[x] = Wt + (size_t)(1024 + Stf[bh*40 + j-NTOP])*1024; zj[x] = 1.f; }
      else if (j == NJ)  { pj[x] = bias; zj[x] = 1.f; }
      else               { pj[x] = Wt;   zj[x] = 0.f; }
    }
    int d = tid & 63, mp = tid >> 6;
    int m0 = (mc << 8) + mp;
    float a0=0.f, a1=0.f, a2=0.f, a3=0.f;
    #pragma unroll 16
    for (int i = 0; i < 64; ++i) {
      int m = m0 + (i << 2);
      float vv = values[(((size_t)(b*1024 + m)*8 + h) << 6) + d];
      a0 = fmaf(pj[0][m]*zj[0], vv, a0);
      a1 = fmaf(pj[1][m]*zj[1], vv, a1);
      a2 = fmaf(pj[2][m]*zj[2], vv, a2);
      a3 = fmaf(pj[3][m]*zj[3], vv, a3);
    }
    float4* red = smbuf;
    red[tid] = make_float4(a0, a1, a2, a3);
    __syncthreads();
    int jj = tid >> 6, dd = tid & 63;
    float4 r0 = red[dd], r1 = red[64+dd], r2 = red[128+dd], r3 = red[192+dd];
    float s;
    if (jj == 0)      s = r0.x + r1.x + r2.x + r3.x;
    else if (jj == 1) s = r0.y + r1.y + r2.y + r3.y;
    else if (jj == 2) s = r0.z + r1.z + r2.z + r3.z;
    else              s = r0.w + r1.w + r2.w + r3.w;
    WVp[(size_t)mc*73728 + ((size_t)bh*72 + j0 + jj)*64 + dd] = s;
  } else {                              // ---- k4 ----
    int gid = bid - 1152;
    int bh = gid >> 5;  int m0 = (gid & 31) << 5;
    int b = bh >> 3, h = bh & 7;
    float* qs   = f;                    // 35*64
    float* ts   = f + 2240;
    float* sc   = f + 4480;             // 32*73
    float* invs = f + 6816;             // 32
    for (int i = tid; i < NTOP*64; i += 256) {
      int j = i >> 6, e = i & 63;
      qs[i] = q  [(((size_t)(b*1024 + St [bh*40 + j])*8 + h) << 6) + e];
      ts[i] = tfq[(((size_t)(b*1024 + Stf[bh*40 + j])*8 + h) << 6) + e];
    }
    __syncthreads();
    int mi = tid & 31, g = tid >> 5;
    int br = g >> 2, g4 = g & 3;
    int m = m0 + mi;
    const float* src = br ? tfq : k;
    float4 kr[16];
    const float4* p = reinterpret_cast<const float4*>(
        src + (((size_t)(b*1024 + m)*8 + h) << 6));
    #pragma unroll
    for (int i = 0; i < 16; ++i) kr[i] = p[i];
    const float4* fs4 = reinterpret_cast<const float4*>(br ? ts : qs);
    int sb = br ? NTOP : 0;
    for (int j = g4; j < NTOP; j += 4) {
      float s = 0.f;
      #pragma unroll
      for (int e4 = 0; e4 < 16; ++e4) {
        float4 qv = fs4[j*16 + e4];
        s += qv.x*kr[e4].x + qv.y*kr[e4].y + qv.z*kr[e4].z + qv.w*kr[e4].w;
      }
      sc[mi*73 + sb + j] = s * 0.125f;
    }
    __syncthreads();
    if (tid < 32) {
      float mx = -1e30f;
      for (int j = 0; j < NJ; ++j) mx = fmaxf(mx, sc[tid*73 + j]);
      float sum = 0.f;
      for (int j = 0; j < NJ; ++j) {
        float e = __expf(sc[tid*73 + j] - mx);
        sc[tid*73 + j] = e; sum += e;
      }
      invs[tid] = 1.0f / sum;
    }
    __syncthreads();
    float* Pb = P + ((size_t)bh*1024 + m0)*72;
    for (int i = tid; i < 32*72; i += 256) {
      int mm = i / 72, j = i - mm*72;
      Pb[i] = (j < NJ) ? sc[mm*73 + j] * invs[mm] : 0.f;
    }
  }
}

// ---------------- D4: k6 per-bh, LDS Wv + transposed P chunk ----------------
__global__ __launch_bounds__(256) void k6_out(
    const float* __restrict__ P, const float* __restrict__ WVp,
    float* __restrict__ out) {
  __shared__ float wv[72*64];           // 18432 B
  __shared__ float Pl[72*68];           // 19584 B (pad 68: aligned, 8-way wr conflict only)
  int bh = blockIdx.x, lc = blockIdx.y;
  int l0 = lc << 6;
  int b = bh >> 3, h = bh & 7;
  int tid = threadIdx.x;
  // stage Wv = sum_mc WVp  (coalesced)
  {
    const float* W0 = WVp + (size_t)bh*4608;
    for (int i = tid; i < 4608; i += 256)
      wv[i] = W0[i] + W0[73728 + i] + W0[147456 + i] + W0[221184 + i];
  }
  // stage P chunk transposed: Pl[j*68 + l] = P[bh, l0+l, j]
  {
    const float* Pg = P + ((size_t)bh*1024 + l0)*72;
    for (int i = tid; i < 4608; i += 256) {
      int l = i / 72, j = i - l*72;
      Pl[j*68 + l] = Pg[i];
    }
  }
  __syncthreads();
  int d = tid & 63, lg = tid >> 6;      // 4 l-groups of 16
  int lb = lg << 4;
  float acc[16];
  float base = wv[NJ*64 + d];
  #pragma unroll
  for (int i = 0; i < 16; ++i) acc[i] = base;
  for (int j = 0; j < NJ; ++j) {
    float wvj = wv[j*64 + d];
    const float4* pr = reinterpret_cast<const float4*>(Pl + j*68 + lb);
    float4 p0 = pr[0], p1 = pr[1], p2 = pr[2], p3 = pr[3];
    acc[0]  = fmaf(p0.x, wvj, acc[0]);  acc[1]  = fmaf(p0.y, wvj, acc[1]);
    acc[2]  = fmaf(p0.z, wvj, acc[2]);  acc[3]  = fmaf(p0.w, wvj, acc[3]);
    acc[4]  = fmaf(p1.x, wvj, acc[4]);  acc[5]  = fmaf(p1.y, wvj, acc[5]);
    acc[6]  = fmaf(p1.z, wvj, acc[6]);  acc[7]  = fmaf(p1.w, wvj, acc[7]);
    acc[8]  = fmaf(p2.x, wvj, acc[8]);  acc[9]  = fmaf(p2.y, wvj, acc[9]);
    acc[10] = fmaf(p2.z, wvj, acc[10]); acc[11] = fmaf(p2.w, wvj, acc[11]);
    acc[12] = fmaf(p3.x, wvj, acc[12]); acc[13] = fmaf(p3.y, wvj, acc[13]);
    acc[14] = fmaf(p3.z, wvj, acc[14]); acc[15] = fmaf(p3.w, wvj, acc[15]);
  }
  #pragma unroll
  for (int i = 0; i < 16; ++i) {
    int l = l0 + lb + i;
    out[(((size_t)(b*1024 + l)*8 + h) << 6) + d] = acc[i];
  }
}

extern "C" void kernel_launch(void* const* d_in, const int* in_sizes, int n_in,
                              void* d_out, int out_size, void* d_ws, size_t ws_size,
                              hipStream_t stream) {
  const float* tfq  = (const float*)d_in[0];
  const float* q    = (const float*)d_in[1];
  const float* k    = (const float*)d_in[2];
  const float* v    = (const float*)d_in[3];
  const float* tw   = (const float*)d_in[5];
  const float* tb   = (const float*)d_in[6];
  float* out = (float*)d_out;

  char* ws = (char*)d_ws;
  float* acp = (float*)(ws);                        // 16,777,216
  int*   St  = (int*)  (ws + 16777216);             // 4 KB
  int*   Stf = (int*)  (ws + 16781312);             // 4 KB
  float* Wt  = (float*)(ws + 16785408);             // 8,388,608
  float* P   = (float*)(ws + 25174016);             // 4,718,592
  float* WVp = (float*)(ws + 29892608);             // 1,179,648

  d1_prep<<<1024, 256, 0, stream>>>(q, k, tw, Wt, acp);
  d2_topk<<<32, 1024, 0, stream>>>(acp, tfq, St, Stf);
  d3_mix <<<1664, 256, 0, stream>>>(q, k, tfq, Wt, tb, v, St, Stf, WVp, P);
  k6_out <<<dim3(16, 16), 256, 0, stream>>>(P, WVp, out);
}